// Round 1
// baseline (19364.409 us; speedup 1.0000x reference)
//
#include <hip/hip_runtime.h>
#include <hip/hip_cooperative_groups.h>
#include <stdint.h>

namespace cg = cooperative_groups;

typedef __attribute__((ext_vector_type(8))) short short8;
typedef __attribute__((ext_vector_type(4))) float floatx4;

#define DI __device__ __forceinline__

// Problem dims
constexpr int BB = 64;          // batch
constexpr int SS = 512;         // seq len
constexpr int II = 1024;        // input size
constexpr int HH = 1024;        // hidden size
constexpr int MM = BB * SS;     // 32768 GEMM rows
constexpr int NN = 4 * HH;      // 4096 gate columns (f,i,o,c)

DI unsigned short f2bf(float f) {
  union { float f; unsigned int u; } v; v.f = f;
  unsigned int u = v.u;
  return (unsigned short)((u + 0x7FFFu + ((u >> 16) & 1u)) >> 16);  // RNE
}
DI float bf2f(unsigned short u) {
  union { unsigned int u; float f; } v; v.u = ((unsigned int)u) << 16;
  return v.f;
}
DI float sigmoidf_(float x) { return 1.0f / (1.0f + __expf(-x)); }
DI float tanhf_(float x)    { return 2.0f / (1.0f + __expf(-2.0f * x)) - 1.0f; }

// async global->LDS, 16B per lane. LDS dest is wave-uniform base + lane*16 (HW).
DI void gload_lds16(const unsigned short* g, unsigned short* l) {
  typedef __attribute__((address_space(1))) const void gv_t;
  typedef __attribute__((address_space(3))) void lv_t;
  __builtin_amdgcn_global_load_lds((gv_t*)(uintptr_t)g, (lv_t*)(uintptr_t)l, 16, 0, 0);
}

// ---------------------------------------------------------------------------
// Prep: transpose+cast one fp32 [1024(k)][1024(n)] matrix -> bf16 [n][k]
// ---------------------------------------------------------------------------
__global__ __launch_bounds__(256) void k_transpose_cast(
    const float* __restrict__ src, unsigned short* __restrict__ dst) {
  __shared__ float tile[32][33];
  const int bx = blockIdx.x;              // 32x32 tiles over 1024x1024
  const int n0 = (bx & 31) * 32, k0 = (bx >> 5) * 32;
  const int tx = threadIdx.x & 31, ty = threadIdx.x >> 5;  // 32x8
#pragma unroll
  for (int i = 0; i < 4; ++i)
    tile[ty + i * 8][tx] = src[(size_t)(k0 + ty + i * 8) * 1024 + n0 + tx];
  __syncthreads();
#pragma unroll
  for (int i = 0; i < 4; ++i)
    dst[(size_t)(n0 + ty + i * 8) * 1024 + k0 + tx] = f2bf(tile[tx][ty + i * 8]);
}

// ---------------------------------------------------------------------------
// Prep: cast x fp32 -> bf16 (vectorized 8/thread)
// ---------------------------------------------------------------------------
__global__ __launch_bounds__(256) void k_cast_x(
    const float* __restrict__ src, unsigned short* __restrict__ dst, int n8) {
  int idx = blockIdx.x * 256 + threadIdx.x;
  if (idx >= n8) return;
  const floatx4* s = (const floatx4*)(src + (size_t)idx * 8);
  floatx4 a = s[0], b = s[1];
  short8 o;
  o[0] = (short)f2bf(a[0]); o[1] = (short)f2bf(a[1]);
  o[2] = (short)f2bf(a[2]); o[3] = (short)f2bf(a[3]);
  o[4] = (short)f2bf(b[0]); o[5] = (short)f2bf(b[1]);
  o[6] = (short)f2bf(b[2]); o[7] = (short)f2bf(b[3]);
  *(short8*)(dst + (size_t)idx * 8) = o;
}

// ---------------------------------------------------------------------------
// Phase 1 GEMM: C[m][n] = A[m][k] * Bt[n][k]^T   (bf16 in, fp32 acc, bf16 out)
// m97 structure: 128x128 tile, BK=32, 4 waves (2x2 of 64x64), global_load_lds.
// ---------------------------------------------------------------------------
__global__ __launch_bounds__(256) void k_gemm_xw(
    const unsigned short* __restrict__ A,   // [32768][1024]
    const unsigned short* __restrict__ Bt,  // [4096][1024]
    unsigned short* __restrict__ C)         // [32768][4096]
{
  __shared__ unsigned short As[128 * 32];   // row-major, 64B rows (linear for gload_lds)
  __shared__ unsigned short Bs[128 * 32];
  const int bid = blockIdx.x;
  const int bm = bid & 255;                 // consecutive blocks share the B panel
  const int bn = bid >> 8;
  const int m0 = bm * 128, n0 = bn * 128;
  const int tid = threadIdx.x;
  const int lane = tid & 63, wid = tid >> 6;

  const unsigned short* ga = A  + (size_t)(m0 + (tid >> 2)) * 1024 + (tid & 3) * 8;
  const unsigned short* gb = Bt + (size_t)(n0 + (tid >> 2)) * 1024 + (tid & 3) * 8;
  unsigned short* lA = As + wid * 512;      // wave-uniform LDS bases
  unsigned short* lB = Bs + wid * 512;

  floatx4 acc[4][4] = {};
  const int wm = (wid >> 1) * 64, wn = (wid & 1) * 64;
  const int lr = lane & 15, lk = (lane >> 4) * 8;

  for (int k0 = 0; k0 < 1024; k0 += 32) {
    gload_lds16(ga + k0, lA);                       // A rows 0..63
    gload_lds16(ga + 64 * 1024 + k0, lA + 2048);    // A rows 64..127
    gload_lds16(gb + k0, lB);
    gload_lds16(gb + 64 * 1024 + k0, lB + 2048);
    __syncthreads();
    short8 af[4], bfv[4];
#pragma unroll
    for (int mt = 0; mt < 4; ++mt)
      af[mt] = *(const short8*)(As + (wm + mt * 16 + lr) * 32 + lk);
#pragma unroll
    for (int nt = 0; nt < 4; ++nt)
      bfv[nt] = *(const short8*)(Bs + (wn + nt * 16 + lr) * 32 + lk);
#pragma unroll
    for (int mt = 0; mt < 4; ++mt)
#pragma unroll
      for (int nt = 0; nt < 4; ++nt)
        acc[mt][nt] = __builtin_amdgcn_mfma_f32_16x16x32_bf16(
            af[mt], bfv[nt], acc[mt][nt], 0, 0, 0);
    __syncthreads();
  }

  // epilogue: C/D layout col=lane&15, row=(lane>>4)*4+r
#pragma unroll
  for (int mt = 0; mt < 4; ++mt) {
    const int row = m0 + wm + mt * 16 + (lane >> 4) * 4;
#pragma unroll
    for (int nt = 0; nt < 4; ++nt) {
      const int col = n0 + wn + nt * 16 + lr;
      unsigned short* cp = C + (size_t)row * 4096 + col;
#pragma unroll
      for (int r = 0; r < 4; ++r)
        cp[(size_t)r * 4096] = f2bf(acc[mt][nt][r]);
    }
  }
}

// ---------------------------------------------------------------------------
// Phase 2: recurrence. Cooperative, 256 blocks x 256 threads (4 waves).
// Block owns 4 h-columns -> 16 gate-columns (4 gates x 4 cols).
// Waves split K=1024 into 4x256; U fragments preloaded in VGPRs (loop-invariant).
// One grid.sync per step; h double-buffered bf16 in ws; c lives in a register.
// ---------------------------------------------------------------------------
__global__ __launch_bounds__(256) void k_recurrence(
    const unsigned short* __restrict__ gates,  // [m=b*512+s][4096] bf16
    const unsigned short* __restrict__ Ut,     // [4][1024(n)][1024(k)] bf16
    const float* __restrict__ bF, const float* __restrict__ bI,
    const float* __restrict__ bO, const float* __restrict__ bC,
    unsigned short* __restrict__ hbuf,         // [2][64][1024] bf16
    float* __restrict__ out)                   // ys | h | c
{
  __shared__ float part[4][16][68];            // [wave][n_loc][row(b)] padded
  cg::grid_group grid = cg::this_grid();

  const int bid = blockIdx.x;
  // XCD-chunked: blocks with equal (bid&7) share an XCD and get adjacent columns
  const int jswz = (bid & 7) * 32 + (bid >> 3);
  const int col0 = jswz * 4;
  const int tid = threadIdx.x, lane = tid & 63, w = tid >> 6;
  const int lr = lane & 15, lk = (lane >> 4) * 8;

  // Preload B fragments: lane's n_loc = lane&15 -> gate g=n_loc>>2, col c=n_loc&3
  const int nloc = lr, g = nloc >> 2, c = nloc & 3;
  short8 bfrag[8];
  {
    const unsigned short* up = Ut + ((size_t)(g * 1024 + col0 + c)) * 1024 + w * 256 + lk;
#pragma unroll
    for (int ks = 0; ks < 8; ++ks) bfrag[ks] = *(const short8*)(up + ks * 32);
  }

  // Elementwise identity: thread t -> (b = t>>2, local col = t&3)
  const int eb = tid >> 2, ecl = tid & 3;
  const int hcol = col0 + ecl;
  const float bias0 = bF[hcol], bias1 = bI[hcol], bias2 = bO[hcol], bias3 = bC[hcol];

  float cstate = 0.0f, hval = 0.0f;

  // init h_{-1} = 0 (buffer 0): 256 blocks x 256 threads covers 65536 elems
  hbuf[bid * 256 + tid] = 0;
  grid.sync();

  for (int s = 0; s < SS; ++s) {
    const unsigned short* hp = hbuf + (s & 1) * 65536;        // read prev h
    unsigned short* hw = hbuf + ((s & 1) ^ 1) * 65536;        // write new h

    floatx4 acc[4] = {};
#pragma unroll
    for (int ks = 0; ks < 8; ++ks) {
#pragma unroll
      for (int mt = 0; mt < 4; ++mt) {
        short8 a = *(const short8*)(hp + (size_t)(mt * 16 + lr) * 1024 +
                                    w * 256 + ks * 32 + lk);
        acc[mt] = __builtin_amdgcn_mfma_f32_16x16x32_bf16(a, bfrag[ks], acc[mt], 0, 0, 0);
      }
    }
    // stash K-partials: C/D col=lane&15 (n_loc), row=(lane>>4)*4+r
#pragma unroll
    for (int mt = 0; mt < 4; ++mt)
      *(floatx4*)&part[w][nloc][mt * 16 + (lane >> 4) * 4] = acc[mt];
    __syncthreads();

    // reduce over 4 waves + elementwise gates
    float pre[4];
#pragma unroll
    for (int gg = 0; gg < 4; ++gg) {
      int n = gg * 4 + ecl;
      float v = part[0][n][eb] + part[1][n][eb] + part[2][n][eb] + part[3][n][eb];
      float gx = bf2f(gates[(size_t)(eb * 512 + s) * 4096 + gg * 1024 + hcol]);
      pre[gg] = v + gx + ((gg == 0) ? bias0 : (gg == 1) ? bias1 : (gg == 2) ? bias2 : bias3);
    }
    float fg = sigmoidf_(pre[0]);
    float ig = sigmoidf_(pre[1]);
    float og = sigmoidf_(pre[2]);
    float gc = tanhf_(pre[3]);
    cstate = fg * cstate + ig * gc;
    hval = og * tanhf_(cstate);

    hw[eb * 1024 + hcol] = f2bf(hval);
    out[(size_t)(eb * 512 + s) * 1024 + hcol] = hval;   // ys[b][s][col]

    grid.sync();   // h visible to all XCDs; also guards part[] reuse
  }

  // final (h, c) after ys
  const size_t ys_sz = (size_t)BB * SS * HH;
  out[ys_sz + (size_t)eb * 1024 + hcol] = hval;
  out[ys_sz + 65536 + (size_t)eb * 1024 + hcol] = cstate;
}

// ---------------------------------------------------------------------------
// Host launcher
// ---------------------------------------------------------------------------
extern "C" void kernel_launch(void* const* d_in, const int* in_sizes, int n_in,
                              void* d_out, int out_size, void* d_ws, size_t ws_size,
                              hipStream_t stream) {
  const float* x = (const float*)d_in[0];
  const float* w[4] = { (const float*)d_in[1], (const float*)d_in[4],
                        (const float*)d_in[7], (const float*)d_in[10] };
  const float* u[4] = { (const float*)d_in[2], (const float*)d_in[5],
                        (const float*)d_in[8], (const float*)d_in[11] };
  const float* b[4] = { (const float*)d_in[3], (const float*)d_in[6],
                        (const float*)d_in[9], (const float*)d_in[12] };

  // workspace layout (bytes)
  const size_t OFF_WT = 0;                        //  8 MB  Wt  [4096][1024] bf16
  const size_t OFF_UT = 8u << 20;                 //  8 MB  Ut  [4096][1024] bf16
  const size_t OFF_XB = 16u << 20;                // 64 MB  x   [32768][1024] bf16
  const size_t OFF_GX = 80u << 20;                // 256 MB gates [32768][4096] bf16
  const size_t OFF_HB = (80u << 20) + (256u << 20); // 256 KB h double buffer
  const size_t NEED = OFF_HB + 2 * 65536 * 2;
  if (ws_size < NEED) return;  // insufficient scratch; fail loudly via absmax

  char* ws = (char*)d_ws;
  unsigned short* Wt = (unsigned short*)(ws + OFF_WT);
  unsigned short* Ut = (unsigned short*)(ws + OFF_UT);
  unsigned short* Xb = (unsigned short*)(ws + OFF_XB);
  unsigned short* Gx = (unsigned short*)(ws + OFF_GX);
  unsigned short* Hb = (unsigned short*)(ws + OFF_HB);

  for (int gi = 0; gi < 4; ++gi) {
    k_transpose_cast<<<1024, 256, 0, stream>>>(w[gi], Wt + (size_t)gi * 1024 * 1024);
    k_transpose_cast<<<1024, 256, 0, stream>>>(u[gi], Ut + (size_t)gi * 1024 * 1024);
  }
  k_cast_x<<<(MM * II / 8) / 256, 256, 0, stream>>>(x, Xb, MM * II / 8);
  k_gemm_xw<<<256 * 32, 256, 0, stream>>>(Xb, Wt, Gx);

  // cooperative recurrence
  const unsigned short* gx_p = Gx;
  const unsigned short* ut_p = Ut;
  const float* b0 = b[0]; const float* b1 = b[1];
  const float* b2 = b[2]; const float* b3 = b[3];
  unsigned short* hb_p = Hb;
  float* out_p = (float*)d_out;
  void* args[] = { (void*)&gx_p, (void*)&ut_p, (void*)&b0, (void*)&b1,
                   (void*)&b2, (void*)&b3, (void*)&hb_p, (void*)&out_p };
  hipLaunchCooperativeKernel(k_recurrence, dim3(256), dim3(256), args, 0, stream);
}